// Round 6
// baseline (67.284 us; speedup 1.0000x reference)
//
#include <hip/hip_runtime.h>
#include <math.h>

#define NPIX (512*1024)   // H*W = 524288
#define NB   8
#define KBINS 16
#define CBINS 4
#define NACC 68           // 64 p_cl + 4 p_l  (p_c derived as row-sums of p_cl)
#define BLOCKS 1024
#define TPB 256

__device__ __forceinline__ float fexp2(float x){ return __builtin_amdgcn_exp2f(x); }
__device__ __forceinline__ float frcp (float x){ return __builtin_amdgcn_rcpf(x); }

// One pixel, one batch. Windowed camera: only edges jr-1, jr, jr+1 are
// non-saturated in fp32 (scale 200, bin width 1/16 -> |arg|>=18.75 is exact
// 0/1). Pc window (4 nonzero bins), tails cancel algebraically:
//   P0 = em            (bin jr-2)     em = 2^(-ESTP*(d+1)) <= 2^-9
//   P1 = 1 - em - s0   (bin jr-1)     s0 = sigmoid at nearest edge (full rcp)
//   P2 = s0 - ep       (bin jr)       ep = 2^( ESTP*(d-1)) <= 2^-9
//   P3 = ep            (bin jr+1)
// -> 3 exp2 + 1 rcp instead of 17 exp2 + 17 rcp. Register scatter via
// integer-literal compare chains (no LDS, no atomics, all static indexing).
// Label path identical to the proven absmax=0 version (5 exp2 + 2 rcp).
__device__ __forceinline__ void px1(float gsum, float x0, float x1, float x2, float x3,
                                    float (&Pc)[KBINS], float (&pl)[CBINS])
{
    constexpr float L2E  = 1.4426950408889634f;
    constexpr float ESTP = 12.5f * L2E;
    constexpr float BSC  = 500.0f * L2E;
    constexpr float LSC  = 1000.0f * L2E;

    // ---- camera window ----
    float u  = gsum * (16.0f / 3.0f);
    float jr = rintf(u);
    float d  = u - jr;                          // in [-0.5, 0.5]
    int   ji = (int)jr;                         // 0..16
    float em = fexp2(fmaf(d, -ESTP, -ESTP));    // 2^(-ESTP*(d+1))
    float ep = fexp2(fmaf(d,  ESTP, -ESTP));    // 2^( ESTP*(d-1))
    float s0 = frcp(1.0f + fexp2(-ESTP * d));
    float P0 = em;
    float P1 = 1.0f - em - s0;
    float P2 = s0 - ep;
    float P3 = ep;

    #pragma unroll
    for (int j = 0; j < KBINS; j++) {
        float v = 0.f;
        v = (ji == j + 2) ? P0 : v;
        v = (ji == j + 1) ? P1 : v;
        v = (ji == j    ) ? P2 : v;
        v = (ji == j - 1) ? P3 : v;
        Pc[j] += v;
    }

    // ---- label: soft-argmax (beta=500) + single live edge sigmoid ----
    float m  = fmaxf(fmaxf(x0, x1), fmaxf(x2, x3));
    float mk = m * BSC;
    float e0 = fexp2(fmaf(x0, BSC, -mk));
    float e1 = fexp2(fmaf(x1, BSC, -mk));
    float e2 = fexp2(fmaf(x2, BSC, -mk));
    float e3 = fexp2(fmaf(x3, BSC, -mk));
    float am = fmaf(3.0f, e3, fmaf(2.0f, e2, e1)) * frcp(e0 + e1 + e2 + e3 + 1e-12f);

    float fj = rintf(am + 0.5f);                            // nearest edge (0..4)
    float vv = frcp(1.0f + fexp2((fj - 0.5f - am) * LSC));  // sigma at that edge
    #pragma unroll
    for (int c = 0; c < CBINS; c++) {
        float add = (fj == (float)(c + 1)) ? (1.0f - vv)
                  : (fj == (float)c)       ? vv : 0.0f;
        pl[c] += add;
    }
}

// Kernel 1: 2 consecutive pixels/thread (float2 loads), 8 batches,
// windowed register accumulation, block-reduce 68 stats.
__launch_bounds__(TPB, 4)
__global__ void nid_partial(const float* __restrict__ cam,
                            const float* __restrict__ lab,
                            float* __restrict__ ws)
{
    const int tid = blockIdx.x * TPB + threadIdx.x;   // 262144 threads
    const int n0  = tid * 2;                          // pixel pair (n0, n0+1)

    float Pc0[KBINS], Pc1[KBINS];
    float pl0[CBINS], pl1[CBINS];
    #pragma unroll
    for (int j = 0; j < KBINS; j++) { Pc0[j] = 0.f; Pc1[j] = 0.f; }
    #pragma unroll
    for (int c = 0; c < CBINS; c++) { pl0[c] = 0.f; pl1[c] = 0.f; }

    #pragma unroll
    for (int b = 0; b < NB; b++) {
        const float* cbase = cam + (size_t)(b * 3) * NPIX + n0;
        float2 c0 = *(const float2*)(cbase);
        float2 c1 = *(const float2*)(cbase + NPIX);
        float2 c2 = *(const float2*)(cbase + 2 * NPIX);
        const float* lbase = lab + (size_t)(b * 4) * NPIX + n0;
        float2 a0 = *(const float2*)(lbase);
        float2 a1 = *(const float2*)(lbase + NPIX);
        float2 a2 = *(const float2*)(lbase + 2 * NPIX);
        float2 a3 = *(const float2*)(lbase + 3 * NPIX);

        px1(c0.x + c1.x + c2.x, a0.x, a1.x, a2.x, a3.x, Pc0, pl0);
        px1(c0.y + c1.y + c2.y, a0.y, a1.y, a2.y, a3.y, Pc1, pl1);
    }

    // ---- per-thread outer products ----
    float acc[NACC];
    #pragma unroll
    for (int k = 0; k < KBINS; k++) {
        #pragma unroll
        for (int c = 0; c < CBINS; c++)
            acc[k * 4 + c] = fmaf(Pc0[k], pl0[c], Pc1[k] * pl1[c]);
    }
    #pragma unroll
    for (int c = 0; c < CBINS; c++) acc[64 + c] = pl0[c] + pl1[c];

    // ---- block reduction: 3-step butterfly (8-lane sums) -> LDS -> 68 threads ----
    __shared__ float red[32][NACC];
    const int lane = threadIdx.x & 63;
    const int wv   = threadIdx.x >> 6;

    #pragma unroll
    for (int i = 0; i < NACC; i++) {
        float v = acc[i];
        v += __shfl_xor(v, 1);
        v += __shfl_xor(v, 2);
        v += __shfl_xor(v, 4);
        if ((lane & 7) == 0) red[wv * 8 + (lane >> 3)][i] = v;
    }

    __syncthreads();
    if (threadIdx.x < NACC) {
        float s = 0.f;
        #pragma unroll
        for (int g = 0; g < 32; g++) s += red[g][threadIdx.x];
        ws[(size_t)blockIdx.x * NACC + threadIdx.x] = s;
    }
}

// Kernel 2: reduce 1024 block-partials in double, compute NID scalar.
__global__ void nid_final(const float* __restrict__ ws, float* __restrict__ out)
{
    __shared__ double partA[8][NACC];
    __shared__ double sm[NACC];
    __shared__ double tots[2];
    const int t = threadIdx.x;  // block of 544

    if (t < 8 * NACC) {
        int v = t % NACC;
        int g = t / NACC;
        double s = 0.0;
        #pragma unroll 8
        for (int i = g * 128; i < g * 128 + 128; i++)
            s += (double)ws[(size_t)i * NACC + v];
        partA[g][v] = s;
    }
    __syncthreads();
    if (t < NACC) {
        double s = 0.0;
        #pragma unroll
        for (int g = 0; g < 8; g++) s += partA[g][t];
        sm[t] = s;
    }
    __syncthreads();
    if (t == 0) {
        double a = 0, bb = 0;
        for (int v = 0; v < 64; v++) a += sm[v];
        for (int c = 0; c < 4; c++)  bb += sm[64 + c];
        tots[0] = a; tots[1] = bb;
    }
    __syncthreads();
    if (t < 64) {
        int k = t >> 2, c = t & 3;
        double pcl = sm[t] / tots[0];
        double pc  = (sm[k * 4] + sm[k * 4 + 1] + sm[k * 4 + 2] + sm[k * 4 + 3]) / tots[0];
        double pll = sm[64 + c] / tots[1];
        double lp  = log(pcl + 1e-7);
        double lo  = log(pc * pll + 1e-7);
        double dI  = pcl * (lp - lo);
        double dH  = -pcl * lp;
        #pragma unroll
        for (int mm = 1; mm < 64; mm <<= 1) {
            dI += __shfl_xor(dI, mm);
            dH += __shfl_xor(dH, mm);
        }
        if (t == 0) out[0] = (float)((1.0 - dI / dH - 0.95) * 20.0);
    }
}

extern "C" void kernel_launch(void* const* d_in, const int* in_sizes, int n_in,
                              void* d_out, int out_size, void* d_ws, size_t ws_size,
                              hipStream_t stream)
{
    const float* cam = (const float*)d_in[0];
    const float* lab = (const float*)d_in[1];
    float* ws = (float*)d_ws;

    hipLaunchKernelGGL(nid_partial, dim3(BLOCKS), dim3(TPB), 0, stream, cam, lab, ws);
    hipLaunchKernelGGL(nid_final, dim3(1), dim3(544), 0, stream, ws, (float*)d_out);
}

// Round 7
// 41.755 us; speedup vs baseline: 1.6114x; 1.6114x over previous
//
#include <hip/hip_runtime.h>
#include <math.h>

#define NPIX (512*1024)   // H*W = 524288
#define NB   8
#define KBINS 16
#define CBINS 4
#define NACC 68           // 64 p_cl + 4 p_l  (p_c derived as row-sums of p_cl)
#define BLOCKS 1024
#define TPB 256
#define HROWS 20          // histogram rows: k' = k+2, k in [-2,17]
#define HCOLS 512         // 2 columns per thread: px*256 + t  (bank = t%32, conflict-free)

__device__ __forceinline__ float fexp2(float x){ return __builtin_amdgcn_exp2f(x); }
__device__ __forceinline__ float frcp (float x){ return __builtin_amdgcn_rcpf(x); }

// Windowed camera histogram update (math verified exact in R6, absmax 0.0):
// only edges jr-1, jr, jr+1 are non-saturated in fp32 (scale 200, bin 1/16).
//   P0 = em          (bin jr-2, row jr+0)
//   P1 = 1-em-s0     (bin jr-1, row jr+1)
//   P2 = s0-ep       (bin jr,   row jr+2)
//   P3 = ep          (bin jr+1, row jr+3)
// 3 exp2 + 1 rcp. Accumulate via this thread's private LDS column: the 4 rows
// are ds_read/add/ds_write at base + ji*2048 with immediate offsets -> no
// compare-select chains, no scratch, no atomics, no bank conflicts.
__device__ __forceinline__ void camWin(float gsum, float* __restrict__ colbase)
{
    constexpr float L2E  = 1.4426950408889634f;
    constexpr float ESTP = 12.5f * L2E;
    float u  = gsum * (16.0f / 3.0f);
    float jr = rintf(u);
    float d  = u - jr;                          // [-0.5, 0.5]
    int   ji = (int)jr;                         // 0..16
    float em = fexp2(fmaf(d, -ESTP, -ESTP));    // 2^(-ESTP*(d+1))
    float ep = fexp2(fmaf(d,  ESTP, -ESTP));    // 2^( ESTP*(d-1))
    float s0 = frcp(1.0f + fexp2(-ESTP * d));
    float* p = colbase + ji * HCOLS;
    p[0 * HCOLS] += em;
    p[1 * HCOLS] += 1.0f - em - s0;
    p[2 * HCOLS] += s0 - ep;
    p[3 * HCOLS] += ep;
}

// Label path (proven, absmax 0.0): soft-argmax (beta=500) + single live edge.
__device__ __forceinline__ void labelAccum(float x0, float x1, float x2, float x3,
                                           float (&pl)[CBINS])
{
    constexpr float L2E = 1.4426950408889634f;
    constexpr float BSC = 500.0f * L2E;
    constexpr float LSC = 1000.0f * L2E;
    float m  = fmaxf(fmaxf(x0, x1), fmaxf(x2, x3));
    float mk = m * BSC;
    float e0 = fexp2(fmaf(x0, BSC, -mk));
    float e1 = fexp2(fmaf(x1, BSC, -mk));
    float e2 = fexp2(fmaf(x2, BSC, -mk));
    float e3 = fexp2(fmaf(x3, BSC, -mk));
    float am = fmaf(3.0f, e3, fmaf(2.0f, e2, e1)) * frcp(e0 + e1 + e2 + e3 + 1e-12f);

    float fj = rintf(am + 0.5f);                            // nearest edge (0..4)
    float v  = frcp(1.0f + fexp2((fj - 0.5f - am) * LSC));  // sigma at that edge
    #pragma unroll
    for (int c = 0; c < CBINS; c++) {
        float add = (fj == (float)(c + 1)) ? (1.0f - v)
                  : (fj == (float)c)       ? v : 0.0f;
        pl[c] += add;
    }
}

__launch_bounds__(TPB, 4)
__global__ void nid_partial(const float* __restrict__ cam,
                            const float* __restrict__ lab,
                            float* __restrict__ ws)
{
    __shared__ float buf[HROWS * HCOLS];   // 40960 B -> 4 blocks/CU; reused for reduce

    const int t   = threadIdx.x;
    const int tid = blockIdx.x * TPB + t;
    const int n0  = tid * 2;               // pixel pair (n0, n0+1)

    float* col0 = buf + t;                 // px0 private column
    float* col1 = buf + 256 + t;           // px1 private column

    // zero own columns only -> no barrier needed
    #pragma unroll
    for (int r = 0; r < HROWS; r++) {
        col0[r * HCOLS] = 0.0f;
        col1[r * HCOLS] = 0.0f;
    }

    float pl0[CBINS] = {0.f, 0.f, 0.f, 0.f};
    float pl1[CBINS] = {0.f, 0.f, 0.f, 0.f};

    #pragma unroll
    for (int b = 0; b < NB; b++) {
        const float* cbase = cam + (size_t)(b * 3) * NPIX + n0;
        float2 c0 = *(const float2*)(cbase);
        float2 c1 = *(const float2*)(cbase + NPIX);
        float2 c2 = *(const float2*)(cbase + 2 * NPIX);
        const float* lbase = lab + (size_t)(b * 4) * NPIX + n0;
        float2 a0 = *(const float2*)(lbase);
        float2 a1 = *(const float2*)(lbase + NPIX);
        float2 a2 = *(const float2*)(lbase + 2 * NPIX);
        float2 a3 = *(const float2*)(lbase + 3 * NPIX);

        camWin(c0.x + c1.x + c2.x, col0);
        camWin(c0.y + c1.y + c2.y, col1);
        labelAccum(a0.x, a1.x, a2.x, a3.x, pl0);
        labelAccum(a0.y, a1.y, a2.y, a3.y, pl1);
    }

    // read back batch-summed Pc (bins 0..15 live at rows 2..17)
    float Pc0[KBINS], Pc1[KBINS];
    #pragma unroll
    for (int k = 0; k < KBINS; k++) {
        Pc0[k] = col0[(k + 2) * HCOLS];
        Pc1[k] = col1[(k + 2) * HCOLS];
    }

    // per-thread outer products
    float acc[NACC];
    #pragma unroll
    for (int k = 0; k < KBINS; k++) {
        #pragma unroll
        for (int c = 0; c < CBINS; c++)
            acc[k * 4 + c] = fmaf(Pc0[k], pl0[c], Pc1[k] * pl1[c]);
    }
    #pragma unroll
    for (int c = 0; c < CBINS; c++) acc[64 + c] = pl0[c] + pl1[c];

    // reuse buf as reduction staging (8704 B <= 40960 B)
    __syncthreads();
    float (*red)[NACC] = (float (*)[NACC])buf;
    const int lane = t & 63;
    const int wv   = t >> 6;

    #pragma unroll
    for (int i = 0; i < NACC; i++) {
        float v = acc[i];
        v += __shfl_xor(v, 1);
        v += __shfl_xor(v, 2);
        v += __shfl_xor(v, 4);
        if ((lane & 7) == 0) red[wv * 8 + (lane >> 3)][i] = v;
    }

    __syncthreads();
    if (t < NACC) {
        float s = 0.f;
        #pragma unroll
        for (int g = 0; g < 32; g++) s += red[g][t];
        ws[(size_t)blockIdx.x * NACC + t] = s;
    }
}

// Kernel 2: reduce 1024 block-partials in double, compute NID scalar.
__global__ void nid_final(const float* __restrict__ ws, float* __restrict__ out)
{
    __shared__ double partA[8][NACC];
    __shared__ double sm[NACC];
    __shared__ double tots[2];
    const int t = threadIdx.x;  // block of 544

    if (t < 8 * NACC) {
        int v = t % NACC;
        int g = t / NACC;
        double s = 0.0;
        #pragma unroll 8
        for (int i = g * 128; i < g * 128 + 128; i++)
            s += (double)ws[(size_t)i * NACC + v];
        partA[g][v] = s;
    }
    __syncthreads();
    if (t < NACC) {
        double s = 0.0;
        #pragma unroll
        for (int g = 0; g < 8; g++) s += partA[g][t];
        sm[t] = s;
    }
    __syncthreads();
    if (t == 0) {
        double a = 0, bb = 0;
        for (int v = 0; v < 64; v++) a += sm[v];
        for (int c = 0; c < 4; c++)  bb += sm[64 + c];
        tots[0] = a; tots[1] = bb;
    }
    __syncthreads();
    if (t < 64) {
        int k = t >> 2, c = t & 3;
        double pcl = sm[t] / tots[0];
        double pc  = (sm[k * 4] + sm[k * 4 + 1] + sm[k * 4 + 2] + sm[k * 4 + 3]) / tots[0];
        double pll = sm[64 + c] / tots[1];
        double lp  = log(pcl + 1e-7);
        double lo  = log(pc * pll + 1e-7);
        double dI  = pcl * (lp - lo);
        double dH  = -pcl * lp;
        #pragma unroll
        for (int mm = 1; mm < 64; mm <<= 1) {
            dI += __shfl_xor(dI, mm);
            dH += __shfl_xor(dH, mm);
        }
        if (t == 0) out[0] = (float)((1.0 - dI / dH - 0.95) * 20.0);
    }
}

extern "C" void kernel_launch(void* const* d_in, const int* in_sizes, int n_in,
                              void* d_out, int out_size, void* d_ws, size_t ws_size,
                              hipStream_t stream)
{
    const float* cam = (const float*)d_in[0];
    const float* lab = (const float*)d_in[1];
    float* ws = (float*)d_ws;

    hipLaunchKernelGGL(nid_partial, dim3(BLOCKS), dim3(TPB), 0, stream, cam, lab, ws);
    hipLaunchKernelGGL(nid_final, dim3(1), dim3(544), 0, stream, ws, (float*)d_out);
}

// Round 8
// 40.270 us; speedup vs baseline: 1.6708x; 1.0369x over previous
//
#include <hip/hip_runtime.h>
#include <math.h>

#define NPIX (512*1024)   // H*W = 524288
#define NB   8
#define KBINS 16
#define CBINS 4
#define NACC 68           // 64 p_cl + 4 p_l  (p_c derived as row-sums of p_cl)
#define BLOCKS 1024
#define TPB 256
#define HROWS 20          // histogram rows: k' = k+2, k in [-2,17]
#define HCOLS 512         // 2 columns per thread: px*256 + t  (bank = t%32, conflict-free)

__device__ __forceinline__ float fexp2(float x){ return __builtin_amdgcn_exp2f(x); }
__device__ __forceinline__ float frcp (float x){ return __builtin_amdgcn_rcpf(x); }

// Non-temporal float2 load: every input byte is consumed exactly once, so
// mark lines evict-first (nt) instead of thrashing 117MB through L2/L3.
typedef float vf2 __attribute__((ext_vector_type(2)));
__device__ __forceinline__ vf2 ntload2(const float* p)
{
    return __builtin_nontemporal_load((const vf2*)p);
}

// Windowed camera histogram update (math verified exact, absmax 0.0):
// only edges jr-1, jr, jr+1 are non-saturated in fp32 (scale 200, bin 1/16).
//   P0 = em          (bin jr-2, row jr+0)
//   P1 = 1-em-s0     (bin jr-1, row jr+1)
//   P2 = s0-ep       (bin jr,   row jr+2)
//   P3 = ep          (bin jr+1, row jr+3)
// 3 exp2 + 1 rcp. Accumulate via this thread's private LDS column (bank =
// t%32 -> 2-way aliasing only, free; no atomics, no runtime reg indexing).
__device__ __forceinline__ void camWin(float gsum, float* __restrict__ colbase)
{
    constexpr float L2E  = 1.4426950408889634f;
    constexpr float ESTP = 12.5f * L2E;
    float u  = gsum * (16.0f / 3.0f);
    float jr = rintf(u);
    float d  = u - jr;                          // [-0.5, 0.5]
    int   ji = (int)jr;                         // 0..16
    float em = fexp2(fmaf(d, -ESTP, -ESTP));    // 2^(-ESTP*(d+1))
    float ep = fexp2(fmaf(d,  ESTP, -ESTP));    // 2^( ESTP*(d-1))
    float s0 = frcp(1.0f + fexp2(-ESTP * d));
    float* p = colbase + ji * HCOLS;
    p[0 * HCOLS] += em;
    p[1 * HCOLS] += 1.0f - em - s0;
    p[2 * HCOLS] += s0 - ep;
    p[3 * HCOLS] += ep;
}

// Label path (proven, absmax 0.0): soft-argmax (beta=500) + single live edge.
__device__ __forceinline__ void labelAccum(float x0, float x1, float x2, float x3,
                                           float (&pl)[CBINS])
{
    constexpr float L2E = 1.4426950408889634f;
    constexpr float BSC = 500.0f * L2E;
    constexpr float LSC = 1000.0f * L2E;
    float m  = fmaxf(fmaxf(x0, x1), fmaxf(x2, x3));
    float mk = m * BSC;
    float e0 = fexp2(fmaf(x0, BSC, -mk));
    float e1 = fexp2(fmaf(x1, BSC, -mk));
    float e2 = fexp2(fmaf(x2, BSC, -mk));
    float e3 = fexp2(fmaf(x3, BSC, -mk));
    float am = fmaf(3.0f, e3, fmaf(2.0f, e2, e1)) * frcp(e0 + e1 + e2 + e3 + 1e-12f);

    float fj = rintf(am + 0.5f);                            // nearest edge (0..4)
    float v  = frcp(1.0f + fexp2((fj - 0.5f - am) * LSC));  // sigma at that edge
    #pragma unroll
    for (int c = 0; c < CBINS; c++) {
        float add = (fj == (float)(c + 1)) ? (1.0f - v)
                  : (fj == (float)c)       ? v : 0.0f;
        pl[c] += add;
    }
}

__launch_bounds__(TPB, 4)
__global__ void nid_partial(const float* __restrict__ cam,
                            const float* __restrict__ lab,
                            float* __restrict__ ws)
{
    __shared__ float buf[HROWS * HCOLS];   // 40960 B -> 4 blocks/CU; reused for reduce

    const int t   = threadIdx.x;
    const int tid = blockIdx.x * TPB + t;
    const int n0  = tid * 2;               // pixel pair (n0, n0+1)

    float* col0 = buf + t;                 // px0 private column
    float* col1 = buf + 256 + t;           // px1 private column

    // zero own columns only -> no barrier needed
    #pragma unroll
    for (int r = 0; r < HROWS; r++) {
        col0[r * HCOLS] = 0.0f;
        col1[r * HCOLS] = 0.0f;
    }

    float pl0[CBINS] = {0.f, 0.f, 0.f, 0.f};
    float pl1[CBINS] = {0.f, 0.f, 0.f, 0.f};

    #pragma unroll
    for (int b = 0; b < NB; b++) {
        const float* cbase = cam + (size_t)(b * 3) * NPIX + n0;
        vf2 c0 = ntload2(cbase);
        vf2 c1 = ntload2(cbase + NPIX);
        vf2 c2 = ntload2(cbase + 2 * NPIX);
        const float* lbase = lab + (size_t)(b * 4) * NPIX + n0;
        vf2 a0 = ntload2(lbase);
        vf2 a1 = ntload2(lbase + NPIX);
        vf2 a2 = ntload2(lbase + 2 * NPIX);
        vf2 a3 = ntload2(lbase + 3 * NPIX);

        camWin(c0.x + c1.x + c2.x, col0);
        camWin(c0.y + c1.y + c2.y, col1);
        labelAccum(a0.x, a1.x, a2.x, a3.x, pl0);
        labelAccum(a0.y, a1.y, a2.y, a3.y, pl1);
    }

    // read back batch-summed Pc (bins 0..15 live at rows 2..17)
    float Pc0[KBINS], Pc1[KBINS];
    #pragma unroll
    for (int k = 0; k < KBINS; k++) {
        Pc0[k] = col0[(k + 2) * HCOLS];
        Pc1[k] = col1[(k + 2) * HCOLS];
    }

    // per-thread outer products
    float acc[NACC];
    #pragma unroll
    for (int k = 0; k < KBINS; k++) {
        #pragma unroll
        for (int c = 0; c < CBINS; c++)
            acc[k * 4 + c] = fmaf(Pc0[k], pl0[c], Pc1[k] * pl1[c]);
    }
    #pragma unroll
    for (int c = 0; c < CBINS; c++) acc[64 + c] = pl0[c] + pl1[c];

    // reuse buf as reduction staging (8704 B <= 40960 B)
    __syncthreads();
    float (*red)[NACC] = (float (*)[NACC])buf;
    const int lane = t & 63;
    const int wv   = t >> 6;

    #pragma unroll
    for (int i = 0; i < NACC; i++) {
        float v = acc[i];
        v += __shfl_xor(v, 1);
        v += __shfl_xor(v, 2);
        v += __shfl_xor(v, 4);
        if ((lane & 7) == 0) red[wv * 8 + (lane >> 3)][i] = v;
    }

    __syncthreads();
    if (t < NACC) {
        float s = 0.f;
        #pragma unroll
        for (int g = 0; g < 32; g++) s += red[g][t];
        ws[(size_t)blockIdx.x * NACC + t] = s;
    }
}

// Kernel 2: reduce 1024 block-partials in double, compute NID scalar.
__global__ void nid_final(const float* __restrict__ ws, float* __restrict__ out)
{
    __shared__ double partA[8][NACC];
    __shared__ double sm[NACC];
    __shared__ double tots[2];
    const int t = threadIdx.x;  // block of 544

    if (t < 8 * NACC) {
        int v = t % NACC;
        int g = t / NACC;
        double s = 0.0;
        #pragma unroll 8
        for (int i = g * 128; i < g * 128 + 128; i++)
            s += (double)ws[(size_t)i * NACC + v];
        partA[g][v] = s;
    }
    __syncthreads();
    if (t < NACC) {
        double s = 0.0;
        #pragma unroll
        for (int g = 0; g < 8; g++) s += partA[g][t];
        sm[t] = s;
    }
    __syncthreads();
    if (t == 0) {
        double a = 0, bb = 0;
        for (int v = 0; v < 64; v++) a += sm[v];
        for (int c = 0; c < 4; c++)  bb += sm[64 + c];
        tots[0] = a; tots[1] = bb;
    }
    __syncthreads();
    if (t < 64) {
        int k = t >> 2, c = t & 3;
        double pcl = sm[t] / tots[0];
        double pc  = (sm[k * 4] + sm[k * 4 + 1] + sm[k * 4 + 2] + sm[k * 4 + 3]) / tots[0];
        double pll = sm[64 + c] / tots[1];
        double lp  = log(pcl + 1e-7);
        double lo  = log(pc * pll + 1e-7);
        double dI  = pcl * (lp - lo);
        double dH  = -pcl * lp;
        #pragma unroll
        for (int mm = 1; mm < 64; mm <<= 1) {
            dI += __shfl_xor(dI, mm);
            dH += __shfl_xor(dH, mm);
        }
        if (t == 0) out[0] = (float)((1.0 - dI / dH - 0.95) * 20.0);
    }
}

extern "C" void kernel_launch(void* const* d_in, const int* in_sizes, int n_in,
                              void* d_out, int out_size, void* d_ws, size_t ws_size,
                              hipStream_t stream)
{
    const float* cam = (const float*)d_in[0];
    const float* lab = (const float*)d_in[1];
    float* ws = (float*)d_ws;

    hipLaunchKernelGGL(nid_partial, dim3(BLOCKS), dim3(TPB), 0, stream, cam, lab, ws);
    hipLaunchKernelGGL(nid_final, dim3(1), dim3(544), 0, stream, ws, (float*)d_out);
}

// Round 9
// 37.602 us; speedup vs baseline: 1.7894x; 1.0709x over previous
//
#include <hip/hip_runtime.h>
#include <math.h>

#define NPIX (512*1024)   // H*W = 524288
#define NB   8
#define KBINS 16
#define CBINS 4
#define NACC 68           // 64 p_cl + 4 p_l  (p_c derived as row-sums of p_cl)
#define BLOCKS 1024
#define TPB 256
#define HROWS 20          // histogram rows: k' = k+2, k in [-2,17]
#define HCOLS 512         // 2 columns per thread: px*256 + t  (bank = t%32, conflict-free)

__device__ __forceinline__ float fexp2(float x){ return __builtin_amdgcn_exp2f(x); }
__device__ __forceinline__ float frcp (float x){ return __builtin_amdgcn_rcpf(x); }

typedef float vf2 __attribute__((ext_vector_type(2)));
__device__ __forceinline__ vf2 ntload2(const float* p)
{
    return __builtin_nontemporal_load((const vf2*)p);
}

// One batch's 7 nt float2 loads (3 camera + 4 label planes) for 2 pixels.
struct B7v { vf2 c0, c1, c2, l0, l1, l2, l3; };

__device__ __forceinline__ B7v loadB(const float* __restrict__ cam,
                                     const float* __restrict__ lab,
                                     int n0, int b)
{
    B7v r;
    const float* cb = cam + (size_t)(b * 3) * NPIX + n0;
    r.c0 = ntload2(cb);
    r.c1 = ntload2(cb + NPIX);
    r.c2 = ntload2(cb + 2 * NPIX);
    const float* lb = lab + (size_t)(b * 4) * NPIX + n0;
    r.l0 = ntload2(lb);
    r.l1 = ntload2(lb + NPIX);
    r.l2 = ntload2(lb + 2 * NPIX);
    r.l3 = ntload2(lb + 3 * NPIX);
    return r;
}

// Windowed camera histogram update (math verified exact, absmax 0.0):
// only edges jr-1, jr, jr+1 are non-saturated in fp32 (scale 200, bin 1/16).
// 3 exp2 + 1 rcp; accumulate into this thread's private LDS column
// (bank = t%32 -> 2-way aliasing only, free; no atomics).
__device__ __forceinline__ void camWin(float gsum, float* __restrict__ colbase)
{
    constexpr float L2E  = 1.4426950408889634f;
    constexpr float ESTP = 12.5f * L2E;
    float u  = gsum * (16.0f / 3.0f);
    float jr = rintf(u);
    float d  = u - jr;                          // [-0.5, 0.5]
    int   ji = (int)jr;                         // 0..16
    float em = fexp2(fmaf(d, -ESTP, -ESTP));    // 2^(-ESTP*(d+1))
    float ep = fexp2(fmaf(d,  ESTP, -ESTP));    // 2^( ESTP*(d-1))
    float s0 = frcp(1.0f + fexp2(-ESTP * d));
    float* p = colbase + ji * HCOLS;
    p[0 * HCOLS] += em;
    p[1 * HCOLS] += 1.0f - em - s0;
    p[2 * HCOLS] += s0 - ep;
    p[3 * HCOLS] += ep;
}

// Label path (proven, absmax 0.0): soft-argmax (beta=500) + single live edge.
__device__ __forceinline__ void labelAccum(float x0, float x1, float x2, float x3,
                                           float (&pl)[CBINS])
{
    constexpr float L2E = 1.4426950408889634f;
    constexpr float BSC = 500.0f * L2E;
    constexpr float LSC = 1000.0f * L2E;
    float m  = fmaxf(fmaxf(x0, x1), fmaxf(x2, x3));
    float mk = m * BSC;
    float e0 = fexp2(fmaf(x0, BSC, -mk));
    float e1 = fexp2(fmaf(x1, BSC, -mk));
    float e2 = fexp2(fmaf(x2, BSC, -mk));
    float e3 = fexp2(fmaf(x3, BSC, -mk));
    float am = fmaf(3.0f, e3, fmaf(2.0f, e2, e1)) * frcp(e0 + e1 + e2 + e3 + 1e-12f);

    float fj = rintf(am + 0.5f);                            // nearest edge (0..4)
    float v  = frcp(1.0f + fexp2((fj - 0.5f - am) * LSC));  // sigma at that edge
    #pragma unroll
    for (int c = 0; c < CBINS; c++) {
        float add = (fj == (float)(c + 1)) ? (1.0f - v)
                  : (fj == (float)c)       ? v : 0.0f;
        pl[c] += add;
    }
}

__launch_bounds__(TPB, 4)
__global__ void nid_partial(const float* __restrict__ cam,
                            const float* __restrict__ lab,
                            float* __restrict__ ws)
{
    __shared__ float buf[HROWS * HCOLS];   // 40960 B -> 4 blocks/CU; reused for reduce

    const int t   = threadIdx.x;
    const int tid = blockIdx.x * TPB + t;
    const int n0  = tid * 2;               // pixel pair (n0, n0+1)

    float* col0 = buf + t;                 // px0 private column
    float* col1 = buf + 256 + t;           // px1 private column

    // zero own columns only -> no barrier needed
    #pragma unroll
    for (int r = 0; r < HROWS; r++) {
        col0[r * HCOLS] = 0.0f;
        col1[r * HCOLS] = 0.0f;
    }

    float pl0[CBINS] = {0.f, 0.f, 0.f, 0.f};
    float pl1[CBINS] = {0.f, 0.f, 0.f, 0.f};

    // 4-deep software pipeline: 28 loads (4 batches x 7 planes) in flight.
    B7v p0 = loadB(cam, lab, n0, 0);
    B7v p1 = loadB(cam, lab, n0, 1);
    B7v p2 = loadB(cam, lab, n0, 2);
    B7v p3 = loadB(cam, lab, n0, 3);

    #define PROC(P)                                                   \
        do {                                                          \
            camWin((P).c0.x + (P).c1.x + (P).c2.x, col0);             \
            camWin((P).c0.y + (P).c1.y + (P).c2.y, col1);             \
            labelAccum((P).l0.x, (P).l1.x, (P).l2.x, (P).l3.x, pl0);  \
            labelAccum((P).l0.y, (P).l1.y, (P).l2.y, (P).l3.y, pl1);  \
        } while (0)

    PROC(p0); p0 = loadB(cam, lab, n0, 4);
    PROC(p1); p1 = loadB(cam, lab, n0, 5);
    PROC(p2); p2 = loadB(cam, lab, n0, 6);
    PROC(p3); p3 = loadB(cam, lab, n0, 7);
    PROC(p0);
    PROC(p1);
    PROC(p2);
    PROC(p3);
    #undef PROC

    // read back batch-summed Pc (bins 0..15 live at rows 2..17)
    float Pc0[KBINS], Pc1[KBINS];
    #pragma unroll
    for (int k = 0; k < KBINS; k++) {
        Pc0[k] = col0[(k + 2) * HCOLS];
        Pc1[k] = col1[(k + 2) * HCOLS];
    }

    // per-thread outer products
    float acc[NACC];
    #pragma unroll
    for (int k = 0; k < KBINS; k++) {
        #pragma unroll
        for (int c = 0; c < CBINS; c++)
            acc[k * 4 + c] = fmaf(Pc0[k], pl0[c], Pc1[k] * pl1[c]);
    }
    #pragma unroll
    for (int c = 0; c < CBINS; c++) acc[64 + c] = pl0[c] + pl1[c];

    // reuse buf as reduction staging (8704 B <= 40960 B)
    __syncthreads();
    float (*red)[NACC] = (float (*)[NACC])buf;
    const int lane = t & 63;
    const int wv   = t >> 6;

    #pragma unroll
    for (int i = 0; i < NACC; i++) {
        float v = acc[i];
        v += __shfl_xor(v, 1);
        v += __shfl_xor(v, 2);
        v += __shfl_xor(v, 4);
        if ((lane & 7) == 0) red[wv * 8 + (lane >> 3)][i] = v;
    }

    __syncthreads();
    if (t < NACC) {
        float s = 0.f;
        #pragma unroll
        for (int g = 0; g < 32; g++) s += red[g][t];
        ws[(size_t)blockIdx.x * NACC + t] = s;
    }
}

// Kernel 2: reduce 1024 block-partials in double, compute NID scalar.
__global__ void nid_final(const float* __restrict__ ws, float* __restrict__ out)
{
    __shared__ double partA[8][NACC];
    __shared__ double sm[NACC];
    __shared__ double tots[2];
    const int t = threadIdx.x;  // block of 544

    if (t < 8 * NACC) {
        int v = t % NACC;
        int g = t / NACC;
        double s = 0.0;
        #pragma unroll 8
        for (int i = g * 128; i < g * 128 + 128; i++)
            s += (double)ws[(size_t)i * NACC + v];
        partA[g][v] = s;
    }
    __syncthreads();
    if (t < NACC) {
        double s = 0.0;
        #pragma unroll
        for (int g = 0; g < 8; g++) s += partA[g][t];
        sm[t] = s;
    }
    __syncthreads();
    if (t == 0) {
        double a = 0, bb = 0;
        for (int v = 0; v < 64; v++) a += sm[v];
        for (int c = 0; c < 4; c++)  bb += sm[64 + c];
        tots[0] = a; tots[1] = bb;
    }
    __syncthreads();
    if (t < 64) {
        int k = t >> 2, c = t & 3;
        double pcl = sm[t] / tots[0];
        double pc  = (sm[k * 4] + sm[k * 4 + 1] + sm[k * 4 + 2] + sm[k * 4 + 3]) / tots[0];
        double pll = sm[64 + c] / tots[1];
        double lp  = log(pcl + 1e-7);
        double lo  = log(pc * pll + 1e-7);
        double dI  = pcl * (lp - lo);
        double dH  = -pcl * lp;
        #pragma unroll
        for (int mm = 1; mm < 64; mm <<= 1) {
            dI += __shfl_xor(dI, mm);
            dH += __shfl_xor(dH, mm);
        }
        if (t == 0) out[0] = (float)((1.0 - dI / dH - 0.95) * 20.0);
    }
}

extern "C" void kernel_launch(void* const* d_in, const int* in_sizes, int n_in,
                              void* d_out, int out_size, void* d_ws, size_t ws_size,
                              hipStream_t stream)
{
    const float* cam = (const float*)d_in[0];
    const float* lab = (const float*)d_in[1];
    float* ws = (float*)d_ws;

    hipLaunchKernelGGL(nid_partial, dim3(BLOCKS), dim3(TPB), 0, stream, cam, lab, ws);
    hipLaunchKernelGGL(nid_final, dim3(1), dim3(544), 0, stream, ws, (float*)d_out);
}

// Round 10
// 37.525 us; speedup vs baseline: 1.7931x; 1.0020x over previous
//
#include <hip/hip_runtime.h>
#include <math.h>

#define NPIX (512*1024)   // H*W = 524288
#define NB   8
#define KBINS 16
#define CBINS 4
#define NACC 68           // 64 p_cl + 4 p_l  (p_c derived as row-sums of p_cl)
#define BLOCKS 512        // 512 x 256 thr x 4 px = NPIX
#define TPB 256
#define HROWS 20          // histogram rows: k' = k+2, k in [-2,17]
#define HCOLS 1024        // 4 columns per thread: px*256 + t (bank = t%32, conflict-free)

__device__ __forceinline__ float fexp2(float x){ return __builtin_amdgcn_exp2f(x); }
__device__ __forceinline__ float frcp (float x){ return __builtin_amdgcn_rcpf(x); }

typedef float vf4 __attribute__((ext_vector_type(4)));
__device__ __forceinline__ vf4 ntload4(const float* p)
{
    return __builtin_nontemporal_load((const vf4*)p);
}

// One batch's 7 nt float4 loads (3 camera + 4 label planes) for 4 pixels.
struct B7q { vf4 c0, c1, c2, l0, l1, l2, l3; };

__device__ __forceinline__ B7q loadB(const float* __restrict__ cam,
                                     const float* __restrict__ lab,
                                     int n0, int b)
{
    B7q r;
    const float* cb = cam + (size_t)(b * 3) * NPIX + n0;
    r.c0 = ntload4(cb);
    r.c1 = ntload4(cb + NPIX);
    r.c2 = ntload4(cb + 2 * NPIX);
    const float* lb = lab + (size_t)(b * 4) * NPIX + n0;
    r.l0 = ntload4(lb);
    r.l1 = ntload4(lb + NPIX);
    r.l2 = ntload4(lb + 2 * NPIX);
    r.l3 = ntload4(lb + 3 * NPIX);
    return r;
}

// Windowed camera histogram update (math verified exact, absmax 0.0):
// only edges jr-1, jr, jr+1 are non-saturated in fp32 (scale 200, bin 1/16).
// 3 exp2 + 1 rcp; accumulate into this thread's private LDS column
// (bank = t%32 -> 2-way aliasing only, free; no atomics).
__device__ __forceinline__ void camWin(float gsum, float* __restrict__ colbase)
{
    constexpr float L2E  = 1.4426950408889634f;
    constexpr float ESTP = 12.5f * L2E;
    float u  = gsum * (16.0f / 3.0f);
    float jr = rintf(u);
    float d  = u - jr;                          // [-0.5, 0.5]
    int   ji = (int)jr;                         // 0..16
    float em = fexp2(fmaf(d, -ESTP, -ESTP));    // 2^(-ESTP*(d+1))
    float ep = fexp2(fmaf(d,  ESTP, -ESTP));    // 2^( ESTP*(d-1))
    float s0 = frcp(1.0f + fexp2(-ESTP * d));
    float* p = colbase + ji * HCOLS;
    p[0 * HCOLS] += em;
    p[1 * HCOLS] += 1.0f - em - s0;
    p[2 * HCOLS] += s0 - ep;
    p[3 * HCOLS] += ep;
}

// Label path (proven, absmax 0.0): soft-argmax (beta=500) + single live edge.
__device__ __forceinline__ void labelAccum(float x0, float x1, float x2, float x3,
                                           float (&pl)[CBINS])
{
    constexpr float L2E = 1.4426950408889634f;
    constexpr float BSC = 500.0f * L2E;
    constexpr float LSC = 1000.0f * L2E;
    float m  = fmaxf(fmaxf(x0, x1), fmaxf(x2, x3));
    float mk = m * BSC;
    float e0 = fexp2(fmaf(x0, BSC, -mk));
    float e1 = fexp2(fmaf(x1, BSC, -mk));
    float e2 = fexp2(fmaf(x2, BSC, -mk));
    float e3 = fexp2(fmaf(x3, BSC, -mk));
    float am = fmaf(3.0f, e3, fmaf(2.0f, e2, e1)) * frcp(e0 + e1 + e2 + e3 + 1e-12f);

    float fj = rintf(am + 0.5f);                            // nearest edge (0..4)
    float v  = frcp(1.0f + fexp2((fj - 0.5f - am) * LSC));  // sigma at that edge
    #pragma unroll
    for (int c = 0; c < CBINS; c++) {
        float add = (fj == (float)(c + 1)) ? (1.0f - v)
                  : (fj == (float)c)       ? v : 0.0f;
        pl[c] += add;
    }
}

// 4 px/thread (float4 nt loads, 16B/lane), depth-4 explicit pipeline.
// launch_bounds(256,2): 256-VGPR budget so 28 in-flight loads (112 payload
// VGPRs) actually persist. LDS 80KB -> 2 blocks/CU, 8 waves/CU; latency
// hiding comes from the pipeline (28KB outstanding/wave), not wave count.
__launch_bounds__(TPB, 2)
__global__ void nid_partial(const float* __restrict__ cam,
                            const float* __restrict__ lab,
                            float* __restrict__ ws)
{
    __shared__ float buf[HROWS * HCOLS];   // 81920 B; reused for reduce staging

    const int t   = threadIdx.x;
    const int tid = blockIdx.x * TPB + t;
    const int n0  = tid * 4;               // pixels n0..n0+3

    float* col0 = buf + t;
    float* col1 = buf + 256 + t;
    float* col2 = buf + 512 + t;
    float* col3 = buf + 768 + t;

    // zero own columns only -> no barrier needed
    #pragma unroll
    for (int r = 0; r < HROWS; r++) {
        col0[r * HCOLS] = 0.0f;
        col1[r * HCOLS] = 0.0f;
        col2[r * HCOLS] = 0.0f;
        col3[r * HCOLS] = 0.0f;
    }

    float pl0[CBINS] = {0.f, 0.f, 0.f, 0.f};
    float pl1[CBINS] = {0.f, 0.f, 0.f, 0.f};
    float pl2[CBINS] = {0.f, 0.f, 0.f, 0.f};
    float pl3[CBINS] = {0.f, 0.f, 0.f, 0.f};

    // depth-4 pipeline: 28 float4 loads (4 batches x 7 planes) in flight
    B7q p0 = loadB(cam, lab, n0, 0);
    B7q p1 = loadB(cam, lab, n0, 1);
    B7q p2 = loadB(cam, lab, n0, 2);
    B7q p3 = loadB(cam, lab, n0, 3);

    #define PROC(P)                                                   \
        do {                                                          \
            camWin((P).c0.x + (P).c1.x + (P).c2.x, col0);             \
            camWin((P).c0.y + (P).c1.y + (P).c2.y, col1);             \
            camWin((P).c0.z + (P).c1.z + (P).c2.z, col2);             \
            camWin((P).c0.w + (P).c1.w + (P).c2.w, col3);             \
            labelAccum((P).l0.x, (P).l1.x, (P).l2.x, (P).l3.x, pl0);  \
            labelAccum((P).l0.y, (P).l1.y, (P).l2.y, (P).l3.y, pl1);  \
            labelAccum((P).l0.z, (P).l1.z, (P).l2.z, (P).l3.z, pl2);  \
            labelAccum((P).l0.w, (P).l1.w, (P).l2.w, (P).l3.w, pl3);  \
        } while (0)

    PROC(p0); p0 = loadB(cam, lab, n0, 4);
    PROC(p1); p1 = loadB(cam, lab, n0, 5);
    PROC(p2); p2 = loadB(cam, lab, n0, 6);
    PROC(p3); p3 = loadB(cam, lab, n0, 7);
    PROC(p0);
    PROC(p1);
    PROC(p2);
    PROC(p3);
    #undef PROC

    // read back batch-summed Pc (bins 0..15 live at rows 2..17)
    float Pc0[KBINS], Pc1[KBINS], Pc2[KBINS], Pc3[KBINS];
    #pragma unroll
    for (int k = 0; k < KBINS; k++) {
        Pc0[k] = col0[(k + 2) * HCOLS];
        Pc1[k] = col1[(k + 2) * HCOLS];
        Pc2[k] = col2[(k + 2) * HCOLS];
        Pc3[k] = col3[(k + 2) * HCOLS];
    }

    // per-thread outer products
    float acc[NACC];
    #pragma unroll
    for (int k = 0; k < KBINS; k++) {
        #pragma unroll
        for (int c = 0; c < CBINS; c++)
            acc[k * 4 + c] = fmaf(Pc0[k], pl0[c],
                             fmaf(Pc1[k], pl1[c],
                             fmaf(Pc2[k], pl2[c], Pc3[k] * pl3[c])));
    }
    #pragma unroll
    for (int c = 0; c < CBINS; c++)
        acc[64 + c] = pl0[c] + pl1[c] + pl2[c] + pl3[c];

    // reuse buf as reduction staging (8704 B <= 81920 B)
    __syncthreads();
    float (*red)[NACC] = (float (*)[NACC])buf;
    const int lane = t & 63;
    const int wv   = t >> 6;

    #pragma unroll
    for (int i = 0; i < NACC; i++) {
        float v = acc[i];
        v += __shfl_xor(v, 1);
        v += __shfl_xor(v, 2);
        v += __shfl_xor(v, 4);
        if ((lane & 7) == 0) red[wv * 8 + (lane >> 3)][i] = v;
    }

    __syncthreads();
    if (t < NACC) {
        float s = 0.f;
        #pragma unroll
        for (int g = 0; g < 32; g++) s += red[g][t];
        ws[(size_t)blockIdx.x * NACC + t] = s;
    }
}

// Kernel 2: reduce 512 block-partials in double, compute NID scalar.
__global__ void nid_final(const float* __restrict__ ws, float* __restrict__ out)
{
    __shared__ double partA[8][NACC];
    __shared__ double sm[NACC];
    __shared__ double tots[2];
    const int t = threadIdx.x;  // block of 544

    if (t < 8 * NACC) {
        int v = t % NACC;
        int g = t / NACC;
        double s = 0.0;
        #pragma unroll 8
        for (int i = g * 64; i < g * 64 + 64; i++)
            s += (double)ws[(size_t)i * NACC + v];
        partA[g][v] = s;
    }
    __syncthreads();
    if (t < NACC) {
        double s = 0.0;
        #pragma unroll
        for (int g = 0; g < 8; g++) s += partA[g][t];
        sm[t] = s;
    }
    __syncthreads();
    if (t == 0) {
        double a = 0, bb = 0;
        for (int v = 0; v < 64; v++) a += sm[v];
        for (int c = 0; c < 4; c++)  bb += sm[64 + c];
        tots[0] = a; tots[1] = bb;
    }
    __syncthreads();
    if (t < 64) {
        int k = t >> 2, c = t & 3;
        double pcl = sm[t] / tots[0];
        double pc  = (sm[k * 4] + sm[k * 4 + 1] + sm[k * 4 + 2] + sm[k * 4 + 3]) / tots[0];
        double pll = sm[64 + c] / tots[1];
        double lp  = log(pcl + 1e-7);
        double lo  = log(pc * pll + 1e-7);
        double dI  = pcl * (lp - lo);
        double dH  = -pcl * lp;
        #pragma unroll
        for (int mm = 1; mm < 64; mm <<= 1) {
            dI += __shfl_xor(dI, mm);
            dH += __shfl_xor(dH, mm);
        }
        if (t == 0) out[0] = (float)((1.0 - dI / dH - 0.95) * 20.0);
    }
}

extern "C" void kernel_launch(void* const* d_in, const int* in_sizes, int n_in,
                              void* d_out, int out_size, void* d_ws, size_t ws_size,
                              hipStream_t stream)
{
    const float* cam = (const float*)d_in[0];
    const float* lab = (const float*)d_in[1];
    float* ws = (float*)d_ws;

    hipLaunchKernelGGL(nid_partial, dim3(BLOCKS), dim3(TPB), 0, stream, cam, lab, ws);
    hipLaunchKernelGGL(nid_final, dim3(1), dim3(544), 0, stream, ws, (float*)d_out);
}